// Round 2
// baseline (2200.596 us; speedup 1.0000x reference)
//
#include <hip/hip_runtime.h>
#include <math.h>

#define BDIM 256
constexpr int B_ = 4, H_ = 768, W_ = 768;
constexpr int HW_ = H_ * W_;                 // 589824
constexpr int BLOCKS_PER_IMG = HW_ / BDIM;   // 2304
constexpr int IH = H_ + 1, IW = W_ + 1;      // 769

// ---------------------------------------------------------------------------
// Conv 3x3 (dilated, SAME) + bias, NHWC, SINGLE SAMPLE. One thread per pixel
// computing all COUT channels. Emits per-block partial sums for InstanceNorm.
// ---------------------------------------------------------------------------
template <int CIN, int COUT, int DIL>
__global__ __launch_bounds__(BDIM) void conv_in_stats(
    const float* __restrict__ in,    // [H][W][CIN]
    const float* __restrict__ wgt,   // [COUT][CIN][3][3]
    const float* __restrict__ bias,  // [COUT]
    float* __restrict__ y,           // [H][W][COUT]
    float* __restrict__ partials)    // [BLOCKS_PER_IMG][2*COUT]
{
    const int blk = blockIdx.x;
    const int pix = blk * BDIM + threadIdx.x;
    const int i = pix / W_, j = pix - i * W_;

    float acc[COUT];
#pragma unroll
    for (int co = 0; co < COUT; ++co) acc[co] = bias[co];

#pragma unroll
    for (int ky = 0; ky < 3; ++ky) {
        const int r = i + (ky - 1) * DIL;
        if (r < 0 || r >= H_) continue;
#pragma unroll
        for (int kx = 0; kx < 3; ++kx) {
            const int c = j + (kx - 1) * DIL;
            if (c < 0 || c >= W_) continue;
            const float* p = in + ((size_t)r * W_ + c) * CIN;
            float iv[CIN];
            if constexpr (CIN % 4 == 0) {
#pragma unroll
                for (int q = 0; q < CIN / 4; ++q) {
                    float4 t = reinterpret_cast<const float4*>(p)[q];
                    iv[4 * q + 0] = t.x; iv[4 * q + 1] = t.y;
                    iv[4 * q + 2] = t.z; iv[4 * q + 3] = t.w;
                }
            } else {
#pragma unroll
                for (int ci = 0; ci < CIN; ++ci) iv[ci] = p[ci];
            }
#pragma unroll
            for (int ci = 0; ci < CIN; ++ci) {
#pragma unroll
                for (int co = 0; co < COUT; ++co)
                    acc[co] = fmaf(iv[ci], wgt[(co * CIN + ci) * 9 + ky * 3 + kx], acc[co]);
            }
        }
    }

    float* yp = y + (size_t)pix * COUT;
#pragma unroll
    for (int q = 0; q < COUT / 4; ++q) {
        float4 t;
        t.x = acc[4 * q]; t.y = acc[4 * q + 1]; t.z = acc[4 * q + 2]; t.w = acc[4 * q + 3];
        reinterpret_cast<float4*>(yp)[q] = t;
    }

    __shared__ float sred[4][2 * COUT];
    const int lane = threadIdx.x & 63, wave = threadIdx.x >> 6;
#pragma unroll
    for (int co = 0; co < COUT; ++co) {
        float s1 = acc[co], s2 = acc[co] * acc[co];
#pragma unroll
        for (int off = 32; off; off >>= 1) {
            s1 += __shfl_xor(s1, off);
            s2 += __shfl_xor(s2, off);
        }
        if (lane == 0) { sred[wave][co] = s1; sred[wave][COUT + co] = s2; }
    }
    __syncthreads();
    if (threadIdx.x < 2 * COUT) {
        float v = sred[0][threadIdx.x] + sred[1][threadIdx.x] +
                  sred[2][threadIdx.x] + sred[3][threadIdx.x];
        partials[(size_t)blk * (2 * COUT) + threadIdx.x] = v;
    }
}

// ---------------------------------------------------------------------------
// Reduce per-block partials -> mean, invstd per channel (single sample)
// ---------------------------------------------------------------------------
template <int COUT>
__global__ __launch_bounds__(BDIM) void reduce_stats(
    const float* __restrict__ partials, float* __restrict__ stats)  // [COUT][2]
{
    const int co = blockIdx.x;
    float s1 = 0.f, s2 = 0.f;
    for (int k = threadIdx.x; k < BLOCKS_PER_IMG; k += BDIM) {
        const float* p = partials + (size_t)k * (2 * COUT);
        s1 += p[co];
        s2 += p[COUT + co];
    }
#pragma unroll
    for (int off = 32; off; off >>= 1) {
        s1 += __shfl_xor(s1, off);
        s2 += __shfl_xor(s2, off);
    }
    __shared__ float l1[4], l2[4];
    const int lane = threadIdx.x & 63, wave = threadIdx.x >> 6;
    if (lane == 0) { l1[wave] = s1; l2[wave] = s2; }
    __syncthreads();
    if (threadIdx.x == 0) {
        float t1 = l1[0] + l1[1] + l1[2] + l1[3];
        float t2 = l2[0] + l2[1] + l2[2] + l2[3];
        float m = t1 / (float)HW_;
        float var = t2 / (float)HW_ - m * m;
        stats[co * 2 + 0] = m;
        stats[co * 2 + 1] = rsqrtf(var + 1e-5f);
    }
}

// ---------------------------------------------------------------------------
// InstanceNorm (affine=False) + ReLU, in place, float4-vectorized
// ---------------------------------------------------------------------------
template <int COUT>
__global__ __launch_bounds__(BDIM) void inorm_relu(
    const float* __restrict__ y, const float* __restrict__ stats,
    float* __restrict__ a)
{
    const size_t total4 = (size_t)HW_ * COUT / 4;
    const size_t idx = (size_t)blockIdx.x * BDIM + threadIdx.x;
    if (idx >= total4) return;
    float4 v = reinterpret_cast<const float4*>(y)[idx];
    const int co = (int)((idx * 4) % COUT);
    const float* st = stats + co * 2;
    float4 o;
    o.x = fmaxf((v.x - st[0]) * st[1], 0.f);
    o.y = fmaxf((v.y - st[2]) * st[3], 0.f);
    o.z = fmaxf((v.z - st[4]) * st[5], 0.f);
    o.w = fmaxf((v.w - st[6]) * st[7], 0.f);
    reinterpret_cast<float4*>(a)[idx] = o;
}

// ---------------------------------------------------------------------------
// conv2 (24->6, dil 1) + channel softmax -> f [H][W][6]  (single sample)
// ---------------------------------------------------------------------------
__global__ __launch_bounds__(BDIM) void conv2_softmax(
    const float* __restrict__ in, const float* __restrict__ wgt,
    const float* __restrict__ bias, float* __restrict__ f)
{
    constexpr int CIN = 24, COUT = 6;
    const int pix = blockIdx.x * BDIM + threadIdx.x;
    const int i = pix / W_, j = pix - i * W_;

    float acc[COUT];
#pragma unroll
    for (int co = 0; co < COUT; ++co) acc[co] = bias[co];

#pragma unroll
    for (int ky = 0; ky < 3; ++ky) {
        const int r = i + (ky - 1);
        if (r < 0 || r >= H_) continue;
#pragma unroll
        for (int kx = 0; kx < 3; ++kx) {
            const int c = j + (kx - 1);
            if (c < 0 || c >= W_) continue;
            const float* p = in + ((size_t)r * W_ + c) * CIN;
            float iv[CIN];
#pragma unroll
            for (int q = 0; q < CIN / 4; ++q) {
                float4 t = reinterpret_cast<const float4*>(p)[q];
                iv[4 * q + 0] = t.x; iv[4 * q + 1] = t.y;
                iv[4 * q + 2] = t.z; iv[4 * q + 3] = t.w;
            }
#pragma unroll
            for (int ci = 0; ci < CIN; ++ci) {
#pragma unroll
                for (int co = 0; co < COUT; ++co)
                    acc[co] = fmaf(iv[ci], wgt[(co * CIN + ci) * 9 + ky * 3 + kx], acc[co]);
            }
        }
    }

    float mx = acc[0];
#pragma unroll
    for (int co = 1; co < COUT; ++co) mx = fmaxf(mx, acc[co]);
    float e[COUT], s = 0.f;
#pragma unroll
    for (int co = 0; co < COUT; ++co) { e[co] = __expf(acc[co] - mx); s += e[co]; }
    const float inv = 1.f / s;
    float2* fp2 = reinterpret_cast<float2*>(f + (size_t)pix * 6);
    fp2[0] = make_float2(e[0] * inv, e[1] * inv);
    fp2[1] = make_float2(e[2] * inv, e[3] * inv);
    fp2[2] = make_float2(e[4] * inv, e[5] * inv);
}

// ---------------------------------------------------------------------------
// Integral images of x and x^2 (fp64), single sample.
// ii layout: [IH][IW], ii[r][c] = sum_{i<r, j<c} x[i][j]
// ---------------------------------------------------------------------------
__global__ __launch_bounds__(BDIM) void rowscan(
    const float* __restrict__ x, double* __restrict__ ii1, double* __restrict__ ii2)
{
    const int gwave = (int)((blockIdx.x * (size_t)BDIM + threadIdx.x) >> 6);
    if (gwave >= IH) return;
    const int lane = threadIdx.x & 63;
    const int r = gwave;
    double* r1 = ii1 + (size_t)r * IW;
    double* r2 = ii2 + (size_t)r * IW;
    if (r == 0) {
        for (int j = lane; j < IW; j += 64) { r1[j] = 0.0; r2[j] = 0.0; }
        return;
    }
    const float* xr = x + (size_t)(r - 1) * W_;
    if (lane == 0) { r1[0] = 0.0; r2[0] = 0.0; }
    double c1 = 0.0, c2 = 0.0;
    for (int seg = 0; seg < W_ / 64; ++seg) {
        const float xv = xr[seg * 64 + lane];
        double v1 = (double)xv, v2 = (double)xv * (double)xv;
#pragma unroll
        for (int d = 1; d < 64; d <<= 1) {
            double t1 = __shfl_up(v1, d);
            double t2 = __shfl_up(v2, d);
            if (lane >= d) { v1 += t1; v2 += t2; }
        }
        v1 += c1; v2 += c2;
        r1[seg * 64 + lane + 1] = v1;
        r2[seg * 64 + lane + 1] = v2;
        c1 = __shfl(v1, 63);
        c2 = __shfl(v2, 63);
    }
}

// pass 2: column cumsum in place, one thread per (array, column)
__global__ __launch_bounds__(BDIM) void colscan(
    double* __restrict__ ii1, double* __restrict__ ii2)
{
    const int t = blockIdx.x * BDIM + threadIdx.x;
    if (t >= 2 * IW) return;
    const int which = t / IW;
    const int j = t - which * IW;
    double* p = which ? ii2 : ii1;
    double acc = p[(size_t)1 * IW + j];
    for (int i = 2; i <= H_; ++i) {
        acc += p[(size_t)i * IW + j];
        p[(size_t)i * IW + j] = acc;
    }
}

// ---------------------------------------------------------------------------
// Final: 6 Sauvola thresholds, softmax-weighted sum, out = (x - th1)*alpha
// ---------------------------------------------------------------------------
__global__ __launch_bounds__(BDIM) void sauvola_out(
    const float* __restrict__ x, const float* __restrict__ f,
    const double* __restrict__ ii1, const double* __restrict__ ii2,
    const float* __restrict__ kArr, const float* __restrict__ RArr,
    const float* __restrict__ alphaP, float* __restrict__ outp)
{
    const int pix = blockIdx.x * BDIM + threadIdx.x;  // [0, HW)
    const int i = pix / W_, j = pix - i * W_;
    const float xv = x[pix];
    const float* fp = f + (size_t)pix * 6;
    const float alpha = alphaP[0];

    const int wins[6] = {3, 5, 7, 11, 15, 19};
    float th1 = 0.f;
#pragma unroll
    for (int wi = 0; wi < 6; ++wi) {
        const int r = wins[wi] >> 1;
        const int r0 = max(i - r, 0), r1i = min(i + r, H_ - 1);
        const int c0 = max(j - r, 0), c1 = min(j + r, W_ - 1);
        const float cnt = (float)((r1i - r0 + 1) * (c1 - c0 + 1));
        const double* rt1 = ii1 + (size_t)r0 * IW;
        const double* rb1 = ii1 + (size_t)(r1i + 1) * IW;
        const double* rt2 = ii2 + (size_t)r0 * IW;
        const double* rb2 = ii2 + (size_t)(r1i + 1) * IW;
        const double s1 = rb1[c1 + 1] - rt1[c1 + 1] - rb1[c0] + rt1[c0];
        const double s2 = rb2[c1 + 1] - rt2[c1 + 1] - rb2[c0] + rt2[c0];
        const float invc = 1.f / cnt;
        const float Ex = (float)s1 * invc;
        const float Ex2 = (float)s2 * invc;
        const float dev = sqrtf(fmaxf(Ex2 - Ex * Ex, 1e-6f));
        const float th = Ex * (1.f + kArr[wi] * (dev / RArr[wi] - 1.f));
        th1 = fmaf(fp[wi], th, th1);
    }
    outp[pix] = (xv - th1) * alpha;
}

// ---------------------------------------------------------------------------
extern "C" void kernel_launch(void* const* d_in, const int* in_sizes, int n_in,
                              void* d_out, int out_size, void* d_ws, size_t ws_size,
                              hipStream_t stream) {
    const float* x   = (const float*)d_in[0];
    const float* w0  = (const float*)d_in[1];  const float* b0 = (const float*)d_in[2];
    const float* w1  = (const float*)d_in[3];  const float* b1 = (const float*)d_in[4];
    const float* w2  = (const float*)d_in[5];  const float* b2 = (const float*)d_in[6];
    const float* w3  = (const float*)d_in[7];  const float* b3 = (const float*)d_in[8];
    const float* w4  = (const float*)d_in[9];  const float* b4 = (const float*)d_in[10];
    const float* w5  = (const float*)d_in[11]; const float* b5 = (const float*)d_in[12];
    const float* wf  = (const float*)d_in[13]; const float* bf = (const float*)d_in[14];
    const float* kA  = (const float*)d_in[15];
    const float* RA  = (const float*)d_in[16];
    const float* alp = (const float*)d_in[17];
    float* out = (float*)d_out;
    (void)ws_size; (void)n_in; (void)in_sizes; (void)out_size;

    // -------- single-sample workspace (≈104.8 MB total) --------
    char* ws = (char*)d_ws;
    size_t off = 0;
    auto alloc = [&](size_t bytes) -> void* {
        void* p = ws + off;
        off += (bytes + 255) & ~(size_t)255;
        return p;
    };
    float* bufA     = (float*)alloc((size_t)HW_ * 20 * sizeof(float)); // 47.2 MB (C=4,12,20)
    float* bufB     = (float*)alloc((size_t)HW_ * 24 * sizeof(float)); // 56.6 MB (C=8,16,24)
    float* partials = (float*)alloc((size_t)BLOCKS_PER_IMG * 48 * sizeof(float));
    float* stats    = (float*)alloc(48 * sizeof(float));
    // After the last conv consumes bufA(20ch), fbuf + both integral images
    // are carved out of the (dead) bufA region:
    float*  fbuf = bufA;                                               // 14.2 MB
    double* ii1  = (double*)((char*)bufA + 14155776);                  // 4.73 MB (256-aligned)
    double* ii2  = (double*)((char*)bufA + 14155776 + 4731136);        // 4.73 MB

    const dim3 blk(BDIM);
    const int convGrid = BLOCKS_PER_IMG;  // 2304

    auto normGrid = [](int cout) {
        return (int)(((size_t)HW_ * cout / 4 + BDIM - 1) / BDIM);
    };

    for (int b = 0; b < B_; ++b) {
        const float* xb   = x   + (size_t)b * HW_;
        float*       outb = out + (size_t)b * HW_;

        conv_in_stats<1, 4, 1><<<convGrid, blk, 0, stream>>>(xb, w0, b0, bufA, partials);
        reduce_stats<4><<<4, blk, 0, stream>>>(partials, stats);
        inorm_relu<4><<<normGrid(4), blk, 0, stream>>>(bufA, stats, bufA);

        conv_in_stats<4, 8, 2><<<convGrid, blk, 0, stream>>>(bufA, w1, b1, bufB, partials);
        reduce_stats<8><<<8, blk, 0, stream>>>(partials, stats);
        inorm_relu<8><<<normGrid(8), blk, 0, stream>>>(bufB, stats, bufB);

        conv_in_stats<8, 12, 2><<<convGrid, blk, 0, stream>>>(bufB, w2, b2, bufA, partials);
        reduce_stats<12><<<12, blk, 0, stream>>>(partials, stats);
        inorm_relu<12><<<normGrid(12), blk, 0, stream>>>(bufA, stats, bufA);

        conv_in_stats<12, 16, 2><<<convGrid, blk, 0, stream>>>(bufA, w3, b3, bufB, partials);
        reduce_stats<16><<<16, blk, 0, stream>>>(partials, stats);
        inorm_relu<16><<<normGrid(16), blk, 0, stream>>>(bufB, stats, bufB);

        conv_in_stats<16, 20, 2><<<convGrid, blk, 0, stream>>>(bufB, w4, b4, bufA, partials);
        reduce_stats<20><<<20, blk, 0, stream>>>(partials, stats);
        inorm_relu<20><<<normGrid(20), blk, 0, stream>>>(bufA, stats, bufA);

        conv_in_stats<20, 24, 2><<<convGrid, blk, 0, stream>>>(bufA, w5, b5, bufB, partials);
        reduce_stats<24><<<24, blk, 0, stream>>>(partials, stats);
        inorm_relu<24><<<normGrid(24), blk, 0, stream>>>(bufB, stats, bufB);

        // bufA region is now dead -> fbuf / ii1 / ii2 alias into it
        conv2_softmax<<<convGrid, blk, 0, stream>>>(bufB, wf, bf, fbuf);

        rowscan<<<(IH * 64 + BDIM - 1) / BDIM, blk, 0, stream>>>(xb, ii1, ii2);
        colscan<<<(2 * IW + BDIM - 1) / BDIM, blk, 0, stream>>>(ii1, ii2);

        sauvola_out<<<convGrid, blk, 0, stream>>>(xb, fbuf, ii1, ii2, kA, RA, alp, outb);
    }
}